// Round 4
// baseline (1448.526 us; speedup 1.0000x reference)
//
#include <hip/hip_runtime.h>
#include <cstdint>
#include <cstddef>

#define BB   16
#define NN   4096
#define CINN 64
#define KKK  64
#define HIDD 128
#define SSS  1024
#define MAXC 512

typedef __attribute__((ext_vector_type(8))) short short8;
typedef __attribute__((ext_vector_type(4))) float f32x4;
typedef unsigned long long u64;

// Exact f32 squared distance, numpy-style: ((dx*dx + dy*dy) + dz*dz), no FMA contraction.
// MUST stay bit-identical to round-1 (absmax 0.0 proved selection equivalence).
__device__ __forceinline__ float d2_exact(float ax, float ay, float az,
                                          float bx, float by, float bz) {
  float dx = __fsub_rn(ax, bx);
  float dy = __fsub_rn(ay, by);
  float dz = __fsub_rn(az, bz);
  return __fadd_rn(__fadd_rn(__fmul_rn(dx, dx), __fmul_rn(dy, dy)), __fmul_rn(dz, dz));
}

// f32 -> bf16 round-to-nearest-even (no NaN inputs here)
__device__ __forceinline__ unsigned short f2bf(float f) {
  unsigned u = __float_as_uint(f);
  return (unsigned short)((u + 0x7fffu + ((u >> 16) & 1u)) >> 16);
}

// ============ K1: heterogeneous: FPS (blocks 0..15) || y1 (16..8207) || W2 cvt (8208) ============
// launch_bounds(256,1): 512-VGPR budget so FPS per-thread point arrays STAY IN REGISTERS
// (round-3 profile: VGPR_Count=68 => compiler sank 48 LDS re-loads into the 1024-step loop).
__global__ __launch_bounds__(256, 1) void k1_kernel(const float* __restrict__ x,
                                                    const float* __restrict__ pos,
                                                    const float* __restrict__ W1,
                                                    const float* __restrict__ W2,
                                                    int* __restrict__ fps_idx,
                                                    float* __restrict__ y1,
                                                    unsigned short* __restrict__ W2t,
                                                    float* __restrict__ pos_out,
                                                    float* __restrict__ batch_out) {
  __shared__ __align__(16) char smem[49280];
  const int tid = threadIdx.x;
  const int bid = blockIdx.x;

  if (bid < BB) {
    // ---------------- FPS: 256 threads, 16 points/thread in registers ----------------
    float* px = (float*)smem;
    float* py = px + NN;
    float* pz = py + NN;
    u64* slots = (u64*)(pz + NN);  // [2][4] parity-double-buffered wave leaders
    const float* pb = pos + (size_t)bid * NN * 3;
    for (int i = tid; i < NN; i += 256) {
      px[i] = pb[3 * i + 0];
      py[i] = pb[3 * i + 1];
      pz[i] = pb[3 * i + 2];
    }
    #pragma unroll
    for (int kk = 0; kk < 4; ++kk)
      batch_out[bid * SSS + kk * 256 + tid] = (float)bid;
    __syncthreads();

    float qx[16], qy[16], qz[16], md[16];
    #pragma unroll
    for (int j = 0; j < 16; ++j) {
      const int i = j * 256 + tid;
      qx[j] = px[i]; qy[j] = py[i]; qz[j] = pz[i];
      md[j] = __builtin_inff();
    }
    int last = 0;
    if (tid == 0) {
      fps_idx[bid * SSS] = 0;
      pos_out[(size_t)bid * SSS * 3 + 0] = px[0];
      pos_out[(size_t)bid * SSS * 3 + 1] = py[0];
      pos_out[(size_t)bid * SSS * 3 + 2] = pz[0];
    }
    for (int t = 1; t < SSS; ++t) {
      const float lx = px[last], ly = py[last], lz = pz[last];
      float bv = -1.f;
      int bj = 0;
      #pragma unroll
      for (int j = 0; j < 16; ++j) {
        const float d = d2_exact(qx[j], qy[j], qz[j], lx, ly, lz);
        md[j] = fminf(md[j], d);
        if (md[j] > bv) { bv = md[j]; bj = j; }  // strict > : lowest j among ties
      }
      // key = (valbits<<32) | ~idx : u64 max == (max val, lowest idx) == jnp.argmax
      u64 key = ((u64)__float_as_uint(bv) << 32) | (unsigned)(~(bj * 256 + tid));
      #pragma unroll
      for (int off = 32; off >= 1; off >>= 1) {
        u64 o = __shfl_xor(key, off, 64);
        key = o > key ? o : key;
      }
      u64* sl = slots + (t & 1) * 4;
      if ((tid & 63) == 0) sl[tid >> 6] = key;
      __syncthreads();  // single barrier per step (parity buffers kill the WAR hazard)
      u64 k0 = sl[0], k1 = sl[1], k2 = sl[2], k3 = sl[3];
      k0 = k1 > k0 ? k1 : k0;
      k2 = k3 > k2 ? k3 : k2;
      k0 = k2 > k0 ? k2 : k0;
      last = (int)(~(unsigned)(k0 & 0xffffffffull));
      if (tid == 0) {
        fps_idx[bid * SSS + t] = last;
        pos_out[((size_t)bid * SSS + t) * 3 + 0] = px[last];
        pos_out[((size_t)bid * SSS + t) * 3 + 1] = py[last];
        pos_out[((size_t)bid * SSS + t) * 3 + 2] = pz[last];
      }
    }
  } else if (bid < 16 + 8192) {
    // ---------------- y1 = x @ W1[0:64,:]  (8 points per block) ----------------
    float* sW = (float*)smem;             // [64][128]
    float* sx = (float*)(smem + 32768);   // [8][64]
    const int p0 = (bid - 16) * 8;
    for (int e = tid; e < CINN * HIDD; e += 256) sW[e] = W1[e];
    for (int e = tid; e < 8 * CINN; e += 256) sx[e] = x[(size_t)p0 * CINN + e];
    __syncthreads();
    const int h = tid & 127;
    const int pg = (tid >> 7) * 4;
    float a0 = 0.f, a1 = 0.f, a2 = 0.f, a3 = 0.f;
    for (int c = 0; c < CINN; ++c) {
      const float w = sW[c * HIDD + h];
      a0 = fmaf(sx[(pg + 0) * CINN + c], w, a0);
      a1 = fmaf(sx[(pg + 1) * CINN + c], w, a1);
      a2 = fmaf(sx[(pg + 2) * CINN + c], w, a2);
      a3 = fmaf(sx[(pg + 3) * CINN + c], w, a3);
    }
    y1[(size_t)(p0 + pg + 0) * HIDD + h] = a0;
    y1[(size_t)(p0 + pg + 1) * HIDD + h] = a1;
    y1[(size_t)(p0 + pg + 2) * HIDD + h] = a2;
    y1[(size_t)(p0 + pg + 3) * HIDD + h] = a3;
  } else {
    // ---------------- W2 -> W2^T bf16 (for MFMA B-operand) ----------------
    for (int e = tid; e < HIDD * HIDD; e += 256) {
      const int n = e >> 7, hh = e & 127;
      W2t[e] = f2bf(W2[hh * HIDD + n]);   // W2t[n][h]
    }
  }
}

// ============ K2: fused ball query + gather + layer1 + bf16 MFMA layer2 + masked max.
//               2 centers/block, BQ done in-block (one pass over points for both centers) ============
__global__ __launch_bounds__(256) void mlp_kernel(const float* __restrict__ pos,
                                                  const float* __restrict__ y1,
                                                  const float* __restrict__ W1,
                                                  const float* __restrict__ b1,
                                                  const unsigned short* __restrict__ W2t,
                                                  const float* __restrict__ b2,
                                                  const int* __restrict__ fps_idx,
                                                  float* __restrict__ out) {
  // [0,32K)=W2t bf16 swz, [32K,64K)=h1 bf16 swz, [64K,68K)=cd[2][512], [68K,72K)=ci[2][512]
  __shared__ __align__(16) char smem[73728];
  __shared__ float s_ctr[2][3];
  __shared__ int s_sel[2][KKK];
  __shared__ int s_cnt[2], s_scnt[2], s_M[2];
  const int tid = threadIdx.x;
  const int g0 = blockIdx.x * 2;
  const int b = g0 >> 10;
  float* s_cd0 = (float*)(smem + 65536);
  float* s_cd1 = s_cd0 + MAXC;
  int* s_ci0 = (int*)(smem + 69632);
  int* s_ci1 = s_ci0 + MAXC;

  // stage W2t (128 rows x 256B, 16 uint4/row) with 16B XOR swizzle (T2)
  for (int c = tid; c < 2048; c += 256) {
    const int row = c >> 4;
    const int col = (c & 15) << 4;
    const uint4 v = ((const uint4*)W2t)[c];
    *(uint4*)(smem + row * 256 + (col ^ ((row & 7) << 4))) = v;
  }
  if (tid < 2) {
    const int cp = fps_idx[g0 + tid];
    s_ctr[tid][0] = pos[((size_t)b * NN + cp) * 3 + 0];
    s_ctr[tid][1] = pos[((size_t)b * NN + cp) * 3 + 1];
    s_ctr[tid][2] = pos[((size_t)b * NN + cp) * 3 + 2];
    s_cnt[tid] = 0; s_scnt[tid] = 0;
  }
  __syncthreads();

  // ---- BQ phase 1: radius filter + compaction for both centers, one pass over points ----
  const float* pb = pos + (size_t)b * NN * 3;
  const float c0x = s_ctr[0][0], c0y = s_ctr[0][1], c0z = s_ctr[0][2];
  const float c1x = s_ctr[1][0], c1y = s_ctr[1][1], c1z = s_ctr[1][2];
  for (int i = tid; i < NN; i += 256) {
    const float x = pb[3 * i + 0], y = pb[3 * i + 1], z = pb[3 * i + 2];
    const float da = d2_exact(x, y, z, c0x, c0y, c0z);
    const float db = d2_exact(x, y, z, c1x, c1y, c1z);
    if (da <= 0.04f) {
      const int slot = atomicAdd(&s_cnt[0], 1);
      if (slot < MAXC) { s_cd0[slot] = da; s_ci0[slot] = i; }
    }
    if (db <= 0.04f) {
      const int slot = atomicAdd(&s_cnt[1], 1);
      if (slot < MAXC) { s_cd1[slot] = db; s_ci1[slot] = i; }
    }
  }
  __syncthreads();

  // ---- BQ phase 2: exact lex-rank (d2, idx) top-K == lax.top_k tie-break (order-free) ----
  #pragma unroll
  for (int ci = 0; ci < 2; ++ci) {
    const float* cd = ci ? s_cd1 : s_cd0;
    const int* cidx = ci ? s_ci1 : s_ci0;
    const int C = min(s_cnt[ci], MAXC);
    for (int j = tid; j < C; j += 256) {
      const float dj = cd[j];
      const int ij = cidx[j];
      int rank = 0;
      for (int m = 0; m < C; ++m) {
        const float dm = cd[m];
        const int im = cidx[m];
        rank += (dm < dj || (dm == dj && im < ij)) ? 1 : 0;
      }
      if (rank < KKK) s_sel[ci][atomicAdd(&s_scnt[ci], 1)] = ij;
    }
  }
  __syncthreads();
  if (tid < 2) s_M[tid] = s_scnt[tid];  // == min(C, K), >= 1 (center itself in radius)
  __syncthreads();

  // ---- gather + layer-1 correction -> h1 bf16 swizzled in LDS ----
  const int wv = tid >> 6, ln = tid & 63;
  const float2 b1v = *(const float2*)(b1 + ln * 2);
  const float2 wav = *(const float2*)(W1 + 64 * HIDD + ln * 2);
  const float2 wbv = *(const float2*)(W1 + 65 * HIDD + ln * 2);
  const float2 wcv = *(const float2*)(W1 + 66 * HIDD + ln * 2);
  char* Hb = smem + 32768;
  for (int r = wv * 32; r < wv * 32 + 32; ++r) {   // row r: center r>>6, neighbor k=r&63
    const int ci = r >> 6, k = r & 63;
    unsigned val = 0u;
    if (k < s_M[ci]) {
      const int p = s_sel[ci][k];
      const float rx = pb[p * 3 + 0] - s_ctr[ci][0];
      const float ry = pb[p * 3 + 1] - s_ctr[ci][1];
      const float rz = pb[p * 3 + 2] - s_ctr[ci][2];
      const float2 yv = *(const float2*)(y1 + ((size_t)(b * NN + p)) * HIDD + ln * 2);
      float v0 = fmaxf(yv.x + b1v.x + rx * wav.x + ry * wbv.x + rz * wcv.x, 0.f);
      float v1 = fmaxf(yv.y + b1v.y + rx * wav.y + ry * wbv.y + rz * wcv.y, 0.f);
      val = (unsigned)f2bf(v0) | ((unsigned)f2bf(v1) << 16);
    }
    *(unsigned*)(Hb + r * 256 + ((ln * 4) ^ ((r & 7) << 4))) = val;
  }
  __syncthreads();

  // ---- MFMA: wave (mw=center, nw=col-half); 4x4 16x16 tiles; K=128 in 4 steps of 32 ----
  const int mw = wv >> 1, nw = wv & 1;
  const int lr = ln & 15, lg = ln >> 4;
  f32x4 zero = {0.f, 0.f, 0.f, 0.f};
  f32x4 acc[4][4];
  #pragma unroll
  for (int mi = 0; mi < 4; ++mi)
    #pragma unroll
    for (int ni = 0; ni < 4; ++ni) acc[mi][ni] = zero;

  #pragma unroll
  for (int ks = 0; ks < 4; ++ks) {
    short8 af[4], bf_[4];
    #pragma unroll
    for (int mi = 0; mi < 4; ++mi) {
      const int row = mw * 64 + mi * 16 + lr;
      af[mi] = *(const short8*)(Hb + row * 256 + ((ks * 64 + lg * 16) ^ ((row & 7) << 4)));
    }
    #pragma unroll
    for (int ni = 0; ni < 4; ++ni) {
      const int row = nw * 64 + ni * 16 + lr;
      bf_[ni] = *(const short8*)(smem + row * 256 + ((ks * 64 + lg * 16) ^ ((row & 7) << 4)));
    }
    #pragma unroll
    for (int mi = 0; mi < 4; ++mi)
      #pragma unroll
      for (int ni = 0; ni < 4; ++ni)
        acc[mi][ni] = __builtin_amdgcn_mfma_f32_16x16x32_bf16(af[mi], bf_[ni], acc[mi][ni], 0, 0, 0);
  }

  // ---- epilogue: relu(acc+b2), mask k>=M to 0 (relu>=0, k=0 valid => exact), max over k ----
  const int cId = g0 + mw;
  const int Mc = s_M[mw];
  #pragma unroll
  for (int ni = 0; ni < 4; ++ni) {
    const float b2v = b2[nw * 64 + ni * 16 + lr];
    float cm = 0.f;
    #pragma unroll
    for (int mi = 0; mi < 4; ++mi)
      #pragma unroll
      for (int rr = 0; rr < 4; ++rr) {
        const int k = mi * 16 + lg * 4 + rr;   // C layout: col=lane&15, row=(lane>>4)*4+reg
        const float v = fmaxf(acc[mi][ni][rr] + b2v, 0.f);
        cm = fmaxf(cm, k < Mc ? v : 0.f);
      }
    cm = fmaxf(cm, __shfl_xor(cm, 16, 64));
    cm = fmaxf(cm, __shfl_xor(cm, 32, 64));
    if (ln < 16) out[(size_t)cId * HIDD + nw * 64 + ni * 16 + lr] = cm;
  }
}

extern "C" void kernel_launch(void* const* d_in, const int* in_sizes, int n_in,
                              void* d_out, int out_size, void* d_ws, size_t ws_size,
                              hipStream_t stream) {
  const float* x   = (const float*)d_in[0];
  const float* pos = (const float*)d_in[1];
  const float* W1  = (const float*)d_in[3];
  const float* b1  = (const float*)d_in[4];
  const float* W2  = (const float*)d_in[5];
  const float* b2  = (const float*)d_in[6];

  float* out       = (float*)d_out;                   // [B*S, HID]
  float* pos_out   = out + (size_t)BB * SSS * HIDD;   // [B*S, 3]
  float* batch_out = pos_out + (size_t)BB * SSS * 3;  // [B*S]

  int* fps_idx        = (int*)d_ws;                               // 64 KB
  unsigned short* W2t = (unsigned short*)((char*)d_ws + 65536);   // 32 KB
  float* y1           = (float*)((char*)d_ws + 131072);           // 32 MB

  k1_kernel<<<16 + 8192 + 1, 256, 0, stream>>>(x, pos, W1, W2, fps_idx, y1, W2t,
                                               pos_out, batch_out);
  mlp_kernel<<<BB * SSS / 2, 256, 0, stream>>>(pos, y1, W1, b1, W2t, b2,
                                               fps_idx, out);
}

// Round 5
// 1348.587 us; speedup vs baseline: 1.0741x; 1.0741x over previous
//
#include <hip/hip_runtime.h>
#include <cstdint>
#include <cstddef>

#define BB   16
#define NN   4096
#define CINN 64
#define KKK  64
#define HIDD 128
#define SSS  1024
#define MAXC 512

typedef __attribute__((ext_vector_type(8))) short short8;
typedef __attribute__((ext_vector_type(4))) float f32x4;
typedef unsigned long long u64;

// Exact f32 squared distance, numpy-style: ((dx*dx + dy*dy) + dz*dz), no FMA contraction.
// MUST stay bit-identical (absmax 0.0 in round 1 proved selection equivalence).
__device__ __forceinline__ float d2_exact(float ax, float ay, float az,
                                          float bx, float by, float bz) {
  float dx = __fsub_rn(ax, bx);
  float dy = __fsub_rn(ay, by);
  float dz = __fsub_rn(az, bz);
  return __fadd_rn(__fadd_rn(__fmul_rn(dx, dx), __fmul_rn(dy, dy)), __fmul_rn(dz, dz));
}

// f32 -> bf16 round-to-nearest-even (no NaN inputs here)
__device__ __forceinline__ unsigned short f2bf(float f) {
  unsigned u = __float_as_uint(f);
  return (unsigned short)((u + 0x7fffu + ((u >> 16) & 1u)) >> 16);
}

// ============ K1 (512 thr): FPS (blocks 0..15) || y1 (16..4111) || W2 cvt (4112) ============
// FPS: 8 pts/thread -> 32 VGPRs of live state, small enough that the compiler
// keeps it registered even at its default ~68-VGPR occupancy target (round-4
// lesson: launch_bounds does NOT flip the remat heuristic; shrinking state does).
__global__ __launch_bounds__(512, 1) void k1_kernel(const float* __restrict__ x,
                                                    const float* __restrict__ pos,
                                                    const float* __restrict__ W1,
                                                    const float* __restrict__ W2,
                                                    int* __restrict__ fps_idx,
                                                    float* __restrict__ y1,
                                                    unsigned short* __restrict__ W2t,
                                                    float* __restrict__ pos_out,
                                                    float* __restrict__ batch_out) {
  __shared__ __align__(16) char smem[49664];
  const int tid = threadIdx.x;
  const int bid = blockIdx.x;

  if (bid < BB) {
    // ---------------- FPS: 512 threads, 8 points/thread in registers ----------------
    float* px = (float*)smem;
    float* py = px + NN;
    float* pz = py + NN;
    u64* slots = (u64*)(pz + NN);  // [2][8] parity-double-buffered wave leaders
    const float* pb = pos + (size_t)bid * NN * 3;
    for (int i = tid; i < NN; i += 512) {
      px[i] = pb[3 * i + 0];
      py[i] = pb[3 * i + 1];
      pz[i] = pb[3 * i + 2];
    }
    batch_out[bid * SSS + tid] = (float)bid;
    batch_out[bid * SSS + 512 + tid] = (float)bid;
    __syncthreads();

    float qx[8], qy[8], qz[8], md[8];
    #pragma unroll
    for (int j = 0; j < 8; ++j) {
      const int i = j * 512 + tid;
      qx[j] = px[i]; qy[j] = py[i]; qz[j] = pz[i];
      md[j] = __builtin_inff();
    }
    int last = 0;
    if (tid == 0) {
      fps_idx[bid * SSS] = 0;
      pos_out[(size_t)bid * SSS * 3 + 0] = px[0];
      pos_out[(size_t)bid * SSS * 3 + 1] = py[0];
      pos_out[(size_t)bid * SSS * 3 + 2] = pz[0];
    }
    for (int t = 1; t < SSS; ++t) {
      const float lx = px[last], ly = py[last], lz = pz[last];  // LDS broadcast
      float bv = -1.f;
      int bj = 0;
      #pragma unroll
      for (int j = 0; j < 8; ++j) {
        const float d = d2_exact(qx[j], qy[j], qz[j], lx, ly, lz);
        md[j] = fminf(md[j], d);
        if (md[j] > bv) { bv = md[j]; bj = j; }  // strict > : lowest j among ties
      }
      // key = (valbits<<32) | ~idx : u64 max == (max val, lowest idx) == jnp.argmax
      u64 key = ((u64)__float_as_uint(bv) << 32) | (unsigned)(~(bj * 512 + tid));
      #pragma unroll
      for (int off = 32; off >= 1; off >>= 1) {
        u64 o = __shfl_xor(key, off, 64);
        key = o > key ? o : key;
      }
      u64* sl = slots + (t & 1) * 8;
      if ((tid & 63) == 0) sl[tid >> 6] = key;
      __syncthreads();  // single barrier/step (parity buffers kill the WAR hazard)
      // all threads redundantly reduce the 8 leader slots (broadcast reads) -> uniform `last`
      u64 mm = sl[0];
      #pragma unroll
      for (int w = 1; w < 8; ++w) mm = sl[w] > mm ? sl[w] : mm;
      last = (int)(~(unsigned)(mm & 0xffffffffull));
      if (tid == 0) {
        fps_idx[bid * SSS + t] = last;
        pos_out[((size_t)bid * SSS + t) * 3 + 0] = px[last];
        pos_out[((size_t)bid * SSS + t) * 3 + 1] = py[last];
        pos_out[((size_t)bid * SSS + t) * 3 + 2] = pz[last];
      }
    }
  } else if (bid < 16 + 4096) {
    // ---------------- y1 = x @ W1[0:64,:]  (16 points per block, 512 thr) ----------------
    float* sW = (float*)smem;             // [64][128] 32KB
    float* sx = (float*)(smem + 32768);   // [16][64] 4KB
    const int p0 = (bid - 16) * 16;
    for (int e = tid; e < CINN * HIDD; e += 512) sW[e] = W1[e];
    for (int e = tid; e < 16 * CINN; e += 512) sx[e] = x[(size_t)p0 * CINN + e];
    __syncthreads();
    const int h = tid & 127;
    const int pg = (tid >> 7) * 4;
    float a0 = 0.f, a1 = 0.f, a2 = 0.f, a3 = 0.f;
    for (int c = 0; c < CINN; ++c) {
      const float w = sW[c * HIDD + h];
      a0 = fmaf(sx[(pg + 0) * CINN + c], w, a0);
      a1 = fmaf(sx[(pg + 1) * CINN + c], w, a1);
      a2 = fmaf(sx[(pg + 2) * CINN + c], w, a2);
      a3 = fmaf(sx[(pg + 3) * CINN + c], w, a3);
    }
    y1[(size_t)(p0 + pg + 0) * HIDD + h] = a0;
    y1[(size_t)(p0 + pg + 1) * HIDD + h] = a1;
    y1[(size_t)(p0 + pg + 2) * HIDD + h] = a2;
    y1[(size_t)(p0 + pg + 3) * HIDD + h] = a3;
  } else {
    // ---------------- W2 -> W2^T bf16 (for MFMA B-operand) ----------------
    for (int e = tid; e < HIDD * HIDD; e += 512) {
      const int n = e >> 7, hh = e & 127;
      W2t[e] = f2bf(W2[hh * HIDD + n]);   // W2t[n][h]
    }
  }
}

// ============ K2: ball query per center -> nbr set + count (round-3 proven) ============
__global__ __launch_bounds__(256) void bq_kernel(const float* __restrict__ pos,
                                                 const int* __restrict__ fps_idx,
                                                 int* __restrict__ nbr,
                                                 int* __restrict__ cnt) {
  const int g = blockIdx.x, b = g >> 10, tid = threadIdx.x;
  __shared__ float s_cd[MAXC];
  __shared__ int s_ci[MAXC];
  __shared__ int s_cnt, s_scnt;
  if (tid == 0) { s_cnt = 0; s_scnt = 0; }
  const float* pb = pos + (size_t)b * NN * 3;
  const int cpt = fps_idx[g];
  const float cx = pb[cpt * 3 + 0], cy = pb[cpt * 3 + 1], cz = pb[cpt * 3 + 2];
  __syncthreads();
  for (int i = tid; i < NN; i += 256) {
    const float d2 = d2_exact(pb[i * 3 + 0], pb[i * 3 + 1], pb[i * 3 + 2], cx, cy, cz);
    if (d2 <= 0.04f) {
      const int slot = atomicAdd(&s_cnt, 1);
      if (slot < MAXC) { s_cd[slot] = d2; s_ci[slot] = i; }
    }
  }
  __syncthreads();
  const int C = min(s_cnt, MAXC);
  // exact lex-rank (d2, idx) == lax.top_k tie-break; order-independent
  for (int j = tid; j < C; j += 256) {
    const float dj = s_cd[j];
    const int ij = s_ci[j];
    int rank = 0;
    for (int m = 0; m < C; ++m) {
      const float dm = s_cd[m];
      const int im = s_ci[m];
      rank += (dm < dj || (dm == dj && im < ij)) ? 1 : 0;
    }
    if (rank < KKK) nbr[(size_t)g * KKK + atomicAdd(&s_scnt, 1)] = ij;
  }
  __syncthreads();
  if (tid == 0) cnt[g] = s_scnt;
}

// ============ K3: gather + layer1-corr + bf16 MFMA layer2 + masked max (round-3 proven) ============
__global__ __launch_bounds__(256) void mlp_kernel(const float* __restrict__ pos,
                                                  const float* __restrict__ y1,
                                                  const float* __restrict__ W1,
                                                  const float* __restrict__ b1,
                                                  const unsigned short* __restrict__ W2t,
                                                  const float* __restrict__ b2,
                                                  const int* __restrict__ fps_idx,
                                                  const int* __restrict__ nbr,
                                                  const int* __restrict__ cnt,
                                                  float* __restrict__ out) {
  __shared__ __align__(16) char smem[65536];  // [0,32K)=W2t bf16 swz, [32K,64K)=h1 bf16 swz
  __shared__ float s_ctr[2][3];
  __shared__ int s_M[2];
  const int tid = threadIdx.x;
  const int g0 = blockIdx.x * 2;
  const int b = g0 >> 10;

  // stage W2t (128 rows x 256B, 16 uint4/row) with 16B XOR swizzle (T2)
  for (int c = tid; c < 2048; c += 256) {
    const int row = c >> 4;
    const int col = (c & 15) << 4;
    const uint4 v = ((const uint4*)W2t)[c];
    *(uint4*)(smem + row * 256 + (col ^ ((row & 7) << 4))) = v;
  }
  if (tid < 2) {
    s_M[tid] = min(cnt[g0 + tid], KKK);
    const int cp = fps_idx[g0 + tid];
    s_ctr[tid][0] = pos[((size_t)b * NN + cp) * 3 + 0];
    s_ctr[tid][1] = pos[((size_t)b * NN + cp) * 3 + 1];
    s_ctr[tid][2] = pos[((size_t)b * NN + cp) * 3 + 2];
  }
  __syncthreads();

  const int wv = tid >> 6, ln = tid & 63;
  const float2 b1v = *(const float2*)(b1 + ln * 2);
  const float2 wav = *(const float2*)(W1 + 64 * HIDD + ln * 2);
  const float2 wbv = *(const float2*)(W1 + 65 * HIDD + ln * 2);
  const float2 wcv = *(const float2*)(W1 + 66 * HIDD + ln * 2);
  char* Hb = smem + 32768;
  for (int r = wv * 32; r < wv * 32 + 32; ++r) {   // row r: center r>>6, neighbor k=r&63
    const int ci = r >> 6, k = r & 63;
    unsigned val = 0u;
    if (k < s_M[ci]) {
      const int p = nbr[(size_t)(g0 + ci) * KKK + k];
      const float rx = pos[((size_t)b * NN + p) * 3 + 0] - s_ctr[ci][0];
      const float ry = pos[((size_t)b * NN + p) * 3 + 1] - s_ctr[ci][1];
      const float rz = pos[((size_t)b * NN + p) * 3 + 2] - s_ctr[ci][2];
      const float2 yv = *(const float2*)(y1 + ((size_t)(b * NN + p)) * HIDD + ln * 2);
      float v0 = fmaxf(yv.x + b1v.x + rx * wav.x + ry * wbv.x + rz * wcv.x, 0.f);
      float v1 = fmaxf(yv.y + b1v.y + rx * wav.y + ry * wbv.y + rz * wcv.y, 0.f);
      val = (unsigned)f2bf(v0) | ((unsigned)f2bf(v1) << 16);
    }
    *(unsigned*)(Hb + r * 256 + ((ln * 4) ^ ((r & 7) << 4))) = val;
  }
  __syncthreads();

  // MFMA: wave (mw=center, nw=col-half); 4x4 16x16 tiles; K=128 in 4 steps of 32
  const int mw = wv >> 1, nw = wv & 1;
  const int lr = ln & 15, lg = ln >> 4;
  f32x4 zero = {0.f, 0.f, 0.f, 0.f};
  f32x4 acc[4][4];
  #pragma unroll
  for (int mi = 0; mi < 4; ++mi)
    #pragma unroll
    for (int ni = 0; ni < 4; ++ni) acc[mi][ni] = zero;

  #pragma unroll
  for (int ks = 0; ks < 4; ++ks) {
    short8 af[4], bf_[4];
    #pragma unroll
    for (int mi = 0; mi < 4; ++mi) {
      const int row = mw * 64 + mi * 16 + lr;
      af[mi] = *(const short8*)(Hb + row * 256 + ((ks * 64 + lg * 16) ^ ((row & 7) << 4)));
    }
    #pragma unroll
    for (int ni = 0; ni < 4; ++ni) {
      const int row = nw * 64 + ni * 16 + lr;
      bf_[ni] = *(const short8*)(smem + row * 256 + ((ks * 64 + lg * 16) ^ ((row & 7) << 4)));
    }
    #pragma unroll
    for (int mi = 0; mi < 4; ++mi)
      #pragma unroll
      for (int ni = 0; ni < 4; ++ni)
        acc[mi][ni] = __builtin_amdgcn_mfma_f32_16x16x32_bf16(af[mi], bf_[ni], acc[mi][ni], 0, 0, 0);
  }

  // epilogue: relu(acc+b2), mask k>=M to 0 (relu>=0, k=0 valid => exact), max over k
  const int cId = g0 + mw;
  const int Mc = s_M[mw];
  #pragma unroll
  for (int ni = 0; ni < 4; ++ni) {
    const float b2v = b2[nw * 64 + ni * 16 + lr];
    float cm = 0.f;
    #pragma unroll
    for (int mi = 0; mi < 4; ++mi)
      #pragma unroll
      for (int rr = 0; rr < 4; ++rr) {
        const int k = mi * 16 + lg * 4 + rr;   // C layout: col=lane&15, row=(lane>>4)*4+reg
        const float v = fmaxf(acc[mi][ni][rr] + b2v, 0.f);
        cm = fmaxf(cm, k < Mc ? v : 0.f);
      }
    cm = fmaxf(cm, __shfl_xor(cm, 16, 64));
    cm = fmaxf(cm, __shfl_xor(cm, 32, 64));
    if (ln < 16) out[(size_t)cId * HIDD + nw * 64 + ni * 16 + lr] = cm;
  }
}

extern "C" void kernel_launch(void* const* d_in, const int* in_sizes, int n_in,
                              void* d_out, int out_size, void* d_ws, size_t ws_size,
                              hipStream_t stream) {
  const float* x   = (const float*)d_in[0];
  const float* pos = (const float*)d_in[1];
  const float* W1  = (const float*)d_in[3];
  const float* b1  = (const float*)d_in[4];
  const float* W2  = (const float*)d_in[5];
  const float* b2  = (const float*)d_in[6];

  float* out       = (float*)d_out;                   // [B*S, HID]
  float* pos_out   = out + (size_t)BB * SSS * HIDD;   // [B*S, 3]
  float* batch_out = pos_out + (size_t)BB * SSS * 3;  // [B*S]

  int* fps_idx        = (int*)d_ws;                               // 64 KB
  int* cnt            = (int*)((char*)d_ws + 65536);              // 64 KB
  unsigned short* W2t = (unsigned short*)((char*)d_ws + 131072);  // 32 KB
  int* nbr            = (int*)((char*)d_ws + 262144);             // 4 MB
  float* y1           = (float*)((char*)d_ws + 262144 + 4194304); // 32 MB

  k1_kernel<<<16 + 4096 + 1, 512, 0, stream>>>(x, pos, W1, W2, fps_idx, y1, W2t,
                                               pos_out, batch_out);
  bq_kernel<<<BB * SSS, 256, 0, stream>>>(pos, fps_idx, nbr, cnt);
  mlp_kernel<<<BB * SSS / 2, 256, 0, stream>>>(pos, y1, W1, b1, W2t, b2,
                                               fps_idx, nbr, cnt, out);
}

// Round 6
// 1331.821 us; speedup vs baseline: 1.0876x; 1.0126x over previous
//
#include <hip/hip_runtime.h>
#include <cstdint>
#include <cstddef>

#define BB   16
#define NN   4096
#define CINN 64
#define KKK  64
#define HIDD 128
#define SSS  1024
#define MAXC 512

typedef __attribute__((ext_vector_type(8))) short short8;
typedef __attribute__((ext_vector_type(4))) float f32x4;
typedef unsigned long long u64;

// Exact f32 squared distance, numpy-style: ((dx*dx + dy*dy) + dz*dz), no FMA contraction.
// MUST stay bit-identical (absmax 0.0 in round 1 proved selection equivalence).
__device__ __forceinline__ float d2_exact(float ax, float ay, float az,
                                          float bx, float by, float bz) {
  float dx = __fsub_rn(ax, bx);
  float dy = __fsub_rn(ay, by);
  float dz = __fsub_rn(az, bz);
  return __fadd_rn(__fadd_rn(__fmul_rn(dx, dx), __fmul_rn(dy, dy)), __fmul_rn(dz, dz));
}

// f32 -> bf16 round-to-nearest-even (no NaN inputs here)
__device__ __forceinline__ unsigned short f2bf(float f) {
  unsigned u = __float_as_uint(f);
  return (unsigned short)((u + 0x7fffu + ((u >> 16) & 1u)) >> 16);
}

// ============ K1 (512 thr): FPS (blocks 0..15) || y1 (16..4111) || W2 cvt (4112) ============
// FPS: 8 pts/thread. Rounds 4/5 proved the compiler ALWAYS rematerializes the
// coordinate arrays from LDS inside the 1024-step loop (VGPR_Count 68 -> 40),
// costing ~24 ds_read/thread/step. The asm "+v" pin makes the loaded values
// opaquely redefined -> remat is impossible, they must stay in VGPRs.
__global__ __launch_bounds__(512, 1) void k1_kernel(const float* __restrict__ x,
                                                    const float* __restrict__ pos,
                                                    const float* __restrict__ W1,
                                                    const float* __restrict__ W2,
                                                    int* __restrict__ fps_idx,
                                                    float* __restrict__ y1,
                                                    unsigned short* __restrict__ W2t,
                                                    float* __restrict__ pos_out,
                                                    float* __restrict__ batch_out) {
  __shared__ __align__(16) char smem[49664];
  const int tid = threadIdx.x;
  const int bid = blockIdx.x;

  if (bid < BB) {
    // ---------------- FPS: 512 threads, 8 points/thread pinned in registers ----------------
    float* px = (float*)smem;
    float* py = px + NN;
    float* pz = py + NN;
    u64* slots = (u64*)(pz + NN);  // [2][8] parity-double-buffered wave leaders
    const float* pb = pos + (size_t)bid * NN * 3;
    for (int i = tid; i < NN; i += 512) {
      px[i] = pb[3 * i + 0];
      py[i] = pb[3 * i + 1];
      pz[i] = pb[3 * i + 2];
    }
    batch_out[bid * SSS + tid] = (float)bid;
    batch_out[bid * SSS + 512 + tid] = (float)bid;
    __syncthreads();

    float qx[8], qy[8], qz[8], md[8];
    #pragma unroll
    for (int j = 0; j < 8; ++j) {
      const int i = j * 512 + tid;
      qx[j] = px[i]; qy[j] = py[i]; qz[j] = pz[i];
      // anti-remat pin: value is now opaquely redefined, must live in a VGPR
      asm volatile("" : "+v"(qx[j]), "+v"(qy[j]), "+v"(qz[j]));
      md[j] = __builtin_inff();
    }
    int last = 0;
    if (tid == 0) {
      fps_idx[bid * SSS] = 0;
      pos_out[(size_t)bid * SSS * 3 + 0] = px[0];
      pos_out[(size_t)bid * SSS * 3 + 1] = py[0];
      pos_out[(size_t)bid * SSS * 3 + 2] = pz[0];
    }
    for (int t = 1; t < SSS; ++t) {
      const float lx = px[last], ly = py[last], lz = pz[last];  // LDS broadcast
      float bv = -1.f;
      int bj = 0;
      #pragma unroll
      for (int j = 0; j < 8; ++j) {
        const float d = d2_exact(qx[j], qy[j], qz[j], lx, ly, lz);
        md[j] = fminf(md[j], d);
        if (md[j] > bv) { bv = md[j]; bj = j; }  // strict > : lowest j among ties
      }
      // key = (valbits<<32) | ~idx : u64 max == (max val, lowest idx) == jnp.argmax
      u64 key = ((u64)__float_as_uint(bv) << 32) | (unsigned)(~(bj * 512 + tid));
      #pragma unroll
      for (int off = 32; off >= 1; off >>= 1) {
        u64 o = __shfl_xor(key, off, 64);
        key = o > key ? o : key;
      }
      u64* sl = slots + (t & 1) * 8;
      if ((tid & 63) == 0) sl[tid >> 6] = key;
      __syncthreads();  // single barrier/step (parity buffers kill the WAR hazard)
      // all threads redundantly reduce the 8 leader slots (broadcast reads) -> uniform `last`
      u64 mm = sl[0];
      #pragma unroll
      for (int w = 1; w < 8; ++w) mm = sl[w] > mm ? sl[w] : mm;
      last = (int)(~(unsigned)(mm & 0xffffffffull));
      if (tid == 0) {
        fps_idx[bid * SSS + t] = last;
        pos_out[((size_t)bid * SSS + t) * 3 + 0] = px[last];
        pos_out[((size_t)bid * SSS + t) * 3 + 1] = py[last];
        pos_out[((size_t)bid * SSS + t) * 3 + 2] = pz[last];
      }
    }
  } else if (bid < 16 + 4096) {
    // ---------------- y1 = x @ W1[0:64,:]  (16 points per block, 512 thr) ----------------
    float* sW = (float*)smem;             // [64][128] 32KB
    float* sx = (float*)(smem + 32768);   // [16][64] 4KB
    const int p0 = (bid - 16) * 16;
    for (int e = tid; e < CINN * HIDD; e += 512) sW[e] = W1[e];
    for (int e = tid; e < 16 * CINN; e += 512) sx[e] = x[(size_t)p0 * CINN + e];
    __syncthreads();
    const int h = tid & 127;
    const int pg = (tid >> 7) * 4;
    float a0 = 0.f, a1 = 0.f, a2 = 0.f, a3 = 0.f;
    for (int c = 0; c < CINN; ++c) {
      const float w = sW[c * HIDD + h];
      a0 = fmaf(sx[(pg + 0) * CINN + c], w, a0);
      a1 = fmaf(sx[(pg + 1) * CINN + c], w, a1);
      a2 = fmaf(sx[(pg + 2) * CINN + c], w, a2);
      a3 = fmaf(sx[(pg + 3) * CINN + c], w, a3);
    }
    y1[(size_t)(p0 + pg + 0) * HIDD + h] = a0;
    y1[(size_t)(p0 + pg + 1) * HIDD + h] = a1;
    y1[(size_t)(p0 + pg + 2) * HIDD + h] = a2;
    y1[(size_t)(p0 + pg + 3) * HIDD + h] = a3;
  } else {
    // ---------------- W2 -> W2^T bf16 (for MFMA B-operand) ----------------
    for (int e = tid; e < HIDD * HIDD; e += 512) {
      const int n = e >> 7, hh = e & 127;
      W2t[e] = f2bf(W2[hh * HIDD + n]);   // W2t[n][h]
    }
  }
}

// ============ K2: ball query per center -> nbr set + count (round-3 proven) ============
__global__ __launch_bounds__(256) void bq_kernel(const float* __restrict__ pos,
                                                 const int* __restrict__ fps_idx,
                                                 int* __restrict__ nbr,
                                                 int* __restrict__ cnt) {
  const int g = blockIdx.x, b = g >> 10, tid = threadIdx.x;
  __shared__ float s_cd[MAXC];
  __shared__ int s_ci[MAXC];
  __shared__ int s_cnt, s_scnt;
  if (tid == 0) { s_cnt = 0; s_scnt = 0; }
  const float* pb = pos + (size_t)b * NN * 3;
  const int cpt = fps_idx[g];
  const float cx = pb[cpt * 3 + 0], cy = pb[cpt * 3 + 1], cz = pb[cpt * 3 + 2];
  __syncthreads();
  for (int i = tid; i < NN; i += 256) {
    const float d2 = d2_exact(pb[i * 3 + 0], pb[i * 3 + 1], pb[i * 3 + 2], cx, cy, cz);
    if (d2 <= 0.04f) {
      const int slot = atomicAdd(&s_cnt, 1);
      if (slot < MAXC) { s_cd[slot] = d2; s_ci[slot] = i; }
    }
  }
  __syncthreads();
  const int C = min(s_cnt, MAXC);
  // exact lex-rank (d2, idx) == lax.top_k tie-break; order-independent
  for (int j = tid; j < C; j += 256) {
    const float dj = s_cd[j];
    const int ij = s_ci[j];
    int rank = 0;
    for (int m = 0; m < C; ++m) {
      const float dm = s_cd[m];
      const int im = s_ci[m];
      rank += (dm < dj || (dm == dj && im < ij)) ? 1 : 0;
    }
    if (rank < KKK) nbr[(size_t)g * KKK + atomicAdd(&s_scnt, 1)] = ij;
  }
  __syncthreads();
  if (tid == 0) cnt[g] = s_scnt;
}

// ============ K3: gather + layer1-corr + bf16 MFMA layer2 + masked max (round-3 proven) ============
__global__ __launch_bounds__(256) void mlp_kernel(const float* __restrict__ pos,
                                                  const float* __restrict__ y1,
                                                  const float* __restrict__ W1,
                                                  const float* __restrict__ b1,
                                                  const unsigned short* __restrict__ W2t,
                                                  const float* __restrict__ b2,
                                                  const int* __restrict__ fps_idx,
                                                  const int* __restrict__ nbr,
                                                  const int* __restrict__ cnt,
                                                  float* __restrict__ out) {
  __shared__ __align__(16) char smem[65536];  // [0,32K)=W2t bf16 swz, [32K,64K)=h1 bf16 swz
  __shared__ float s_ctr[2][3];
  __shared__ int s_M[2];
  const int tid = threadIdx.x;
  const int g0 = blockIdx.x * 2;
  const int b = g0 >> 10;

  // stage W2t (128 rows x 256B, 16 uint4/row) with 16B XOR swizzle (T2)
  for (int c = tid; c < 2048; c += 256) {
    const int row = c >> 4;
    const int col = (c & 15) << 4;
    const uint4 v = ((const uint4*)W2t)[c];
    *(uint4*)(smem + row * 256 + (col ^ ((row & 7) << 4))) = v;
  }
  if (tid < 2) {
    s_M[tid] = min(cnt[g0 + tid], KKK);
    const int cp = fps_idx[g0 + tid];
    s_ctr[tid][0] = pos[((size_t)b * NN + cp) * 3 + 0];
    s_ctr[tid][1] = pos[((size_t)b * NN + cp) * 3 + 1];
    s_ctr[tid][2] = pos[((size_t)b * NN + cp) * 3 + 2];
  }
  __syncthreads();

  const int wv = tid >> 6, ln = tid & 63;
  const float2 b1v = *(const float2*)(b1 + ln * 2);
  const float2 wav = *(const float2*)(W1 + 64 * HIDD + ln * 2);
  const float2 wbv = *(const float2*)(W1 + 65 * HIDD + ln * 2);
  const float2 wcv = *(const float2*)(W1 + 66 * HIDD + ln * 2);
  char* Hb = smem + 32768;
  for (int r = wv * 32; r < wv * 32 + 32; ++r) {   // row r: center r>>6, neighbor k=r&63
    const int ci = r >> 6, k = r & 63;
    unsigned val = 0u;
    if (k < s_M[ci]) {
      const int p = nbr[(size_t)(g0 + ci) * KKK + k];
      const float rx = pos[((size_t)b * NN + p) * 3 + 0] - s_ctr[ci][0];
      const float ry = pos[((size_t)b * NN + p) * 3 + 1] - s_ctr[ci][1];
      const float rz = pos[((size_t)b * NN + p) * 3 + 2] - s_ctr[ci][2];
      const float2 yv = *(const float2*)(y1 + ((size_t)(b * NN + p)) * HIDD + ln * 2);
      float v0 = fmaxf(yv.x + b1v.x + rx * wav.x + ry * wbv.x + rz * wcv.x, 0.f);
      float v1 = fmaxf(yv.y + b1v.y + rx * wav.y + ry * wbv.y + rz * wcv.y, 0.f);
      val = (unsigned)f2bf(v0) | ((unsigned)f2bf(v1) << 16);
    }
    *(unsigned*)(Hb + r * 256 + ((ln * 4) ^ ((r & 7) << 4))) = val;
  }
  __syncthreads();

  // MFMA: wave (mw=center, nw=col-half); 4x4 16x16 tiles; K=128 in 4 steps of 32
  const int mw = wv >> 1, nw = wv & 1;
  const int lr = ln & 15, lg = ln >> 4;
  f32x4 zero = {0.f, 0.f, 0.f, 0.f};
  f32x4 acc[4][4];
  #pragma unroll
  for (int mi = 0; mi < 4; ++mi)
    #pragma unroll
    for (int ni = 0; ni < 4; ++ni) acc[mi][ni] = zero;

  #pragma unroll
  for (int ks = 0; ks < 4; ++ks) {
    short8 af[4], bf_[4];
    #pragma unroll
    for (int mi = 0; mi < 4; ++mi) {
      const int row = mw * 64 + mi * 16 + lr;
      af[mi] = *(const short8*)(Hb + row * 256 + ((ks * 64 + lg * 16) ^ ((row & 7) << 4)));
    }
    #pragma unroll
    for (int ni = 0; ni < 4; ++ni) {
      const int row = nw * 64 + ni * 16 + lr;
      bf_[ni] = *(const short8*)(smem + row * 256 + ((ks * 64 + lg * 16) ^ ((row & 7) << 4)));
    }
    #pragma unroll
    for (int mi = 0; mi < 4; ++mi)
      #pragma unroll
      for (int ni = 0; ni < 4; ++ni)
        acc[mi][ni] = __builtin_amdgcn_mfma_f32_16x16x32_bf16(af[mi], bf_[ni], acc[mi][ni], 0, 0, 0);
  }

  // epilogue: relu(acc+b2), mask k>=M to 0 (relu>=0, k=0 valid => exact), max over k
  const int cId = g0 + mw;
  const int Mc = s_M[mw];
  #pragma unroll
  for (int ni = 0; ni < 4; ++ni) {
    const float b2v = b2[nw * 64 + ni * 16 + lr];
    float cm = 0.f;
    #pragma unroll
    for (int mi = 0; mi < 4; ++mi)
      #pragma unroll
      for (int rr = 0; rr < 4; ++rr) {
        const int k = mi * 16 + lg * 4 + rr;   // C layout: col=lane&15, row=(lane>>4)*4+reg
        const float v = fmaxf(acc[mi][ni][rr] + b2v, 0.f);
        cm = fmaxf(cm, k < Mc ? v : 0.f);
      }
    cm = fmaxf(cm, __shfl_xor(cm, 16, 64));
    cm = fmaxf(cm, __shfl_xor(cm, 32, 64));
    if (ln < 16) out[(size_t)cId * HIDD + nw * 64 + ni * 16 + lr] = cm;
  }
}

extern "C" void kernel_launch(void* const* d_in, const int* in_sizes, int n_in,
                              void* d_out, int out_size, void* d_ws, size_t ws_size,
                              hipStream_t stream) {
  const float* x   = (const float*)d_in[0];
  const float* pos = (const float*)d_in[1];
  const float* W1  = (const float*)d_in[3];
  const float* b1  = (const float*)d_in[4];
  const float* W2  = (const float*)d_in[5];
  const float* b2  = (const float*)d_in[6];

  float* out       = (float*)d_out;                   // [B*S, HID]
  float* pos_out   = out + (size_t)BB * SSS * HIDD;   // [B*S, 3]
  float* batch_out = pos_out + (size_t)BB * SSS * 3;  // [B*S]

  int* fps_idx        = (int*)d_ws;                               // 64 KB
  int* cnt            = (int*)((char*)d_ws + 65536);              // 64 KB
  unsigned short* W2t = (unsigned short*)((char*)d_ws + 131072);  // 32 KB
  int* nbr            = (int*)((char*)d_ws + 262144);             // 4 MB
  float* y1           = (float*)((char*)d_ws + 262144 + 4194304); // 32 MB

  k1_kernel<<<16 + 4096 + 1, 512, 0, stream>>>(x, pos, W1, W2, fps_idx, y1, W2t,
                                               pos_out, batch_out);
  bq_kernel<<<BB * SSS, 256, 0, stream>>>(pos, fps_idx, nbr, cnt);
  mlp_kernel<<<BB * SSS / 2, 256, 0, stream>>>(pos, y1, W1, b1, W2t, b2,
                                               fps_idx, nbr, cnt, out);
}

// Round 7
// 1198.055 us; speedup vs baseline: 1.2091x; 1.1117x over previous
//
#include <hip/hip_runtime.h>
#include <cstdint>
#include <cstddef>

#define BB   16
#define NN   4096
#define CINN 64
#define KKK  64
#define HIDD 128
#define SSS  1024
#define MAXC 512

typedef __attribute__((ext_vector_type(8))) short short8;
typedef __attribute__((ext_vector_type(4))) float f32x4;
typedef unsigned long long u64;

// Exact f32 squared distance, numpy-style: ((dx*dx + dy*dy) + dz*dz), no FMA contraction.
// MUST stay bit-identical (absmax 0.0 in round 1 proved selection equivalence).
__device__ __forceinline__ float d2_exact(float ax, float ay, float az,
                                          float bx, float by, float bz) {
  float dx = __fsub_rn(ax, bx);
  float dy = __fsub_rn(ay, by);
  float dz = __fsub_rn(az, bz);
  return __fadd_rn(__fadd_rn(__fmul_rn(dx, dx), __fmul_rn(dy, dy)), __fmul_rn(dz, dz));
}

// f32 -> bf16 round-to-nearest-even (no NaN inputs here)
__device__ __forceinline__ unsigned short f2bf(float f) {
  unsigned u = __float_as_uint(f);
  return (unsigned short)((u + 0x7fffu + ((u >> 16) & 1u)) >> 16);
}

// ============ K1 (512 thr): FPS (blocks 0..15) || y1 (16..4111) || W2 cvt (4112) ============
// FPS round-6 lesson: time was CONSTANT across 16/8 pts-per-thread layouts -> the loop is
// latency-bound on the 6-stage ds_bpermute shuffle chain (~720 cyc/step), not VALU/remat.
// This round: u64 argmax reduce via DPP (VALU pipe, ~80 cyc) to lane 63, rocPRIM-style.
__global__ __launch_bounds__(512, 1) void k1_kernel(const float* __restrict__ x,
                                                    const float* __restrict__ pos,
                                                    const float* __restrict__ W1,
                                                    const float* __restrict__ W2,
                                                    int* __restrict__ fps_idx,
                                                    float* __restrict__ y1,
                                                    unsigned short* __restrict__ W2t,
                                                    float* __restrict__ pos_out,
                                                    float* __restrict__ batch_out) {
  __shared__ __align__(16) char smem[49664];
  const int tid = threadIdx.x;
  const int bid = blockIdx.x;

  if (bid < BB) {
    // ---------------- FPS: 512 threads, 8 points/thread in registers ----------------
    float* px = (float*)smem;
    float* py = px + NN;
    float* pz = py + NN;
    u64* slots = (u64*)(pz + NN);  // [2][8] parity-double-buffered wave leaders
    const float* pb = pos + (size_t)bid * NN * 3;
    for (int i = tid; i < NN; i += 512) {
      px[i] = pb[3 * i + 0];
      py[i] = pb[3 * i + 1];
      pz[i] = pb[3 * i + 2];
    }
    batch_out[bid * SSS + tid] = (float)bid;
    batch_out[bid * SSS + 512 + tid] = (float)bid;
    __syncthreads();

    float qx[8], qy[8], qz[8], md[8];
    #pragma unroll
    for (int j = 0; j < 8; ++j) {
      const int i = j * 512 + tid;
      qx[j] = px[i]; qy[j] = py[i]; qz[j] = pz[i];
      asm volatile("" : "+v"(qx[j]), "+v"(qy[j]), "+v"(qz[j]));
      md[j] = __builtin_inff();
    }
    int last = 0;
    if (tid == 0) {
      fps_idx[bid * SSS] = 0;
      pos_out[(size_t)bid * SSS * 3 + 0] = px[0];
      pos_out[(size_t)bid * SSS * 3 + 1] = py[0];
      pos_out[(size_t)bid * SSS * 3 + 2] = pz[0];
    }
    for (int t = 1; t < SSS; ++t) {
      const float lx = px[last], ly = py[last], lz = pz[last];  // LDS broadcast
      float bv = -1.f;
      int bj = 0;
      #pragma unroll
      for (int j = 0; j < 8; ++j) {
        const float d = d2_exact(qx[j], qy[j], qz[j], lx, ly, lz);
        md[j] = fminf(md[j], d);
        if (md[j] > bv) { bv = md[j]; bj = j; }  // strict > : lowest j among ties
      }
      // key = (valbits<<32) | ~idx : u64 max == (max val, lowest idx) == jnp.argmax
      unsigned klo = ~(unsigned)(bj * 512 + tid);
      unsigned khi = __float_as_uint(bv);
      // DPP wavefront max-reduce to lane 63 (all-VALU; old=0 & bound_ctrl -> masked/invalid
      // lanes contribute 0, identity for unsigned max). Same u64-max semantics as butterfly.
#define FPS_DPP_STAGE(CTRL, RMASK)                                                            \
      {                                                                                        \
        unsigned slo = (unsigned)__builtin_amdgcn_update_dpp(0, (int)klo, CTRL, RMASK, 0xf, true); \
        unsigned shi = (unsigned)__builtin_amdgcn_update_dpp(0, (int)khi, CTRL, RMASK, 0xf, true); \
        if ((((u64)shi << 32) | slo) > (((u64)khi << 32) | klo)) { khi = shi; klo = slo; }     \
      }
      FPS_DPP_STAGE(0x111, 0xf)  // row_shr:1
      FPS_DPP_STAGE(0x112, 0xf)  // row_shr:2
      FPS_DPP_STAGE(0x114, 0xf)  // row_shr:4
      FPS_DPP_STAGE(0x118, 0xf)  // row_shr:8  -> lane15/31/47/63 hold row maxes
      FPS_DPP_STAGE(0x142, 0xa)  // row_bcast:15 -> rows 1,3: lane31/63 = half maxes
      FPS_DPP_STAGE(0x143, 0xc)  // row_bcast:31 -> rows 2,3: lane63 = wave max
#undef FPS_DPP_STAGE
      u64* sl = slots + (t & 1) * 8;
      if ((tid & 63) == 63) sl[tid >> 6] = ((u64)khi << 32) | klo;
      __syncthreads();  // single barrier/step (parity buffers kill the WAR hazard)
      // all threads redundantly reduce the 8 leader slots (broadcast reads) -> uniform `last`
      u64 mm = sl[0];
      #pragma unroll
      for (int w = 1; w < 8; ++w) mm = sl[w] > mm ? sl[w] : mm;
      last = (int)(~(unsigned)(mm & 0xffffffffull));
      if (tid == 0) {
        fps_idx[bid * SSS + t] = last;
        pos_out[((size_t)bid * SSS + t) * 3 + 0] = px[last];
        pos_out[((size_t)bid * SSS + t) * 3 + 1] = py[last];
        pos_out[((size_t)bid * SSS + t) * 3 + 2] = pz[last];
      }
    }
  } else if (bid < 16 + 4096) {
    // ---------------- y1 = x @ W1[0:64,:]  (16 points per block, 512 thr) ----------------
    float* sW = (float*)smem;             // [64][128] 32KB
    float* sx = (float*)(smem + 32768);   // [16][64] 4KB
    const int p0 = (bid - 16) * 16;
    for (int e = tid; e < CINN * HIDD; e += 512) sW[e] = W1[e];
    for (int e = tid; e < 16 * CINN; e += 512) sx[e] = x[(size_t)p0 * CINN + e];
    __syncthreads();
    const int h = tid & 127;
    const int pg = (tid >> 7) * 4;
    float a0 = 0.f, a1 = 0.f, a2 = 0.f, a3 = 0.f;
    for (int c = 0; c < CINN; ++c) {
      const float w = sW[c * HIDD + h];
      a0 = fmaf(sx[(pg + 0) * CINN + c], w, a0);
      a1 = fmaf(sx[(pg + 1) * CINN + c], w, a1);
      a2 = fmaf(sx[(pg + 2) * CINN + c], w, a2);
      a3 = fmaf(sx[(pg + 3) * CINN + c], w, a3);
    }
    y1[(size_t)(p0 + pg + 0) * HIDD + h] = a0;
    y1[(size_t)(p0 + pg + 1) * HIDD + h] = a1;
    y1[(size_t)(p0 + pg + 2) * HIDD + h] = a2;
    y1[(size_t)(p0 + pg + 3) * HIDD + h] = a3;
  } else {
    // ---------------- W2 -> W2^T bf16 (for MFMA B-operand) ----------------
    for (int e = tid; e < HIDD * HIDD; e += 512) {
      const int n = e >> 7, hh = e & 127;
      W2t[e] = f2bf(W2[hh * HIDD + n]);   // W2t[n][h]
    }
  }
}

// ============ K2: ball query per center -> nbr set + count (round-3 proven) ============
__global__ __launch_bounds__(256) void bq_kernel(const float* __restrict__ pos,
                                                 const int* __restrict__ fps_idx,
                                                 int* __restrict__ nbr,
                                                 int* __restrict__ cnt) {
  const int g = blockIdx.x, b = g >> 10, tid = threadIdx.x;
  __shared__ float s_cd[MAXC];
  __shared__ int s_ci[MAXC];
  __shared__ int s_cnt, s_scnt;
  if (tid == 0) { s_cnt = 0; s_scnt = 0; }
  const float* pb = pos + (size_t)b * NN * 3;
  const int cpt = fps_idx[g];
  const float cx = pb[cpt * 3 + 0], cy = pb[cpt * 3 + 1], cz = pb[cpt * 3 + 2];
  __syncthreads();
  for (int i = tid; i < NN; i += 256) {
    const float d2 = d2_exact(pb[i * 3 + 0], pb[i * 3 + 1], pb[i * 3 + 2], cx, cy, cz);
    if (d2 <= 0.04f) {
      const int slot = atomicAdd(&s_cnt, 1);
      if (slot < MAXC) { s_cd[slot] = d2; s_ci[slot] = i; }
    }
  }
  __syncthreads();
  const int C = min(s_cnt, MAXC);
  // exact lex-rank (d2, idx) == lax.top_k tie-break; order-independent
  for (int j = tid; j < C; j += 256) {
    const float dj = s_cd[j];
    const int ij = s_ci[j];
    int rank = 0;
    for (int m = 0; m < C; ++m) {
      const float dm = s_cd[m];
      const int im = s_ci[m];
      rank += (dm < dj || (dm == dj && im < ij)) ? 1 : 0;
    }
    if (rank < KKK) nbr[(size_t)g * KKK + atomicAdd(&s_scnt, 1)] = ij;
  }
  __syncthreads();
  if (tid == 0) cnt[g] = s_scnt;
}

// ============ K3: gather + layer1-corr + bf16 MFMA layer2 + masked max (round-3 proven) ============
__global__ __launch_bounds__(256) void mlp_kernel(const float* __restrict__ pos,
                                                  const float* __restrict__ y1,
                                                  const float* __restrict__ W1,
                                                  const float* __restrict__ b1,
                                                  const unsigned short* __restrict__ W2t,
                                                  const float* __restrict__ b2,
                                                  const int* __restrict__ fps_idx,
                                                  const int* __restrict__ nbr,
                                                  const int* __restrict__ cnt,
                                                  float* __restrict__ out) {
  __shared__ __align__(16) char smem[65536];  // [0,32K)=W2t bf16 swz, [32K,64K)=h1 bf16 swz
  __shared__ float s_ctr[2][3];
  __shared__ int s_M[2];
  const int tid = threadIdx.x;
  const int g0 = blockIdx.x * 2;
  const int b = g0 >> 10;

  // stage W2t (128 rows x 256B, 16 uint4/row) with 16B XOR swizzle (T2)
  for (int c = tid; c < 2048; c += 256) {
    const int row = c >> 4;
    const int col = (c & 15) << 4;
    const uint4 v = ((const uint4*)W2t)[c];
    *(uint4*)(smem + row * 256 + (col ^ ((row & 7) << 4))) = v;
  }
  if (tid < 2) {
    s_M[tid] = min(cnt[g0 + tid], KKK);
    const int cp = fps_idx[g0 + tid];
    s_ctr[tid][0] = pos[((size_t)b * NN + cp) * 3 + 0];
    s_ctr[tid][1] = pos[((size_t)b * NN + cp) * 3 + 1];
    s_ctr[tid][2] = pos[((size_t)b * NN + cp) * 3 + 2];
  }
  __syncthreads();

  const int wv = tid >> 6, ln = tid & 63;
  const float2 b1v = *(const float2*)(b1 + ln * 2);
  const float2 wav = *(const float2*)(W1 + 64 * HIDD + ln * 2);
  const float2 wbv = *(const float2*)(W1 + 65 * HIDD + ln * 2);
  const float2 wcv = *(const float2*)(W1 + 66 * HIDD + ln * 2);
  char* Hb = smem + 32768;
  for (int r = wv * 32; r < wv * 32 + 32; ++r) {   // row r: center r>>6, neighbor k=r&63
    const int ci = r >> 6, k = r & 63;
    unsigned val = 0u;
    if (k < s_M[ci]) {
      const int p = nbr[(size_t)(g0 + ci) * KKK + k];
      const float rx = pos[((size_t)b * NN + p) * 3 + 0] - s_ctr[ci][0];
      const float ry = pos[((size_t)b * NN + p) * 3 + 1] - s_ctr[ci][1];
      const float rz = pos[((size_t)b * NN + p) * 3 + 2] - s_ctr[ci][2];
      const float2 yv = *(const float2*)(y1 + ((size_t)(b * NN + p)) * HIDD + ln * 2);
      float v0 = fmaxf(yv.x + b1v.x + rx * wav.x + ry * wbv.x + rz * wcv.x, 0.f);
      float v1 = fmaxf(yv.y + b1v.y + rx * wav.y + ry * wbv.y + rz * wcv.y, 0.f);
      val = (unsigned)f2bf(v0) | ((unsigned)f2bf(v1) << 16);
    }
    *(unsigned*)(Hb + r * 256 + ((ln * 4) ^ ((r & 7) << 4))) = val;
  }
  __syncthreads();

  // MFMA: wave (mw=center, nw=col-half); 4x4 16x16 tiles; K=128 in 4 steps of 32
  const int mw = wv >> 1, nw = wv & 1;
  const int lr = ln & 15, lg = ln >> 4;
  f32x4 zero = {0.f, 0.f, 0.f, 0.f};
  f32x4 acc[4][4];
  #pragma unroll
  for (int mi = 0; mi < 4; ++mi)
    #pragma unroll
    for (int ni = 0; ni < 4; ++ni) acc[mi][ni] = zero;

  #pragma unroll
  for (int ks = 0; ks < 4; ++ks) {
    short8 af[4], bf_[4];
    #pragma unroll
    for (int mi = 0; mi < 4; ++mi) {
      const int row = mw * 64 + mi * 16 + lr;
      af[mi] = *(const short8*)(Hb + row * 256 + ((ks * 64 + lg * 16) ^ ((row & 7) << 4)));
    }
    #pragma unroll
    for (int ni = 0; ni < 4; ++ni) {
      const int row = nw * 64 + ni * 16 + lr;
      bf_[ni] = *(const short8*)(smem + row * 256 + ((ks * 64 + lg * 16) ^ ((row & 7) << 4)));
    }
    #pragma unroll
    for (int mi = 0; mi < 4; ++mi)
      #pragma unroll
      for (int ni = 0; ni < 4; ++ni)
        acc[mi][ni] = __builtin_amdgcn_mfma_f32_16x16x32_bf16(af[mi], bf_[ni], acc[mi][ni], 0, 0, 0);
  }

  // epilogue: relu(acc+b2), mask k>=M to 0 (relu>=0, k=0 valid => exact), max over k
  const int cId = g0 + mw;
  const int Mc = s_M[mw];
  #pragma unroll
  for (int ni = 0; ni < 4; ++ni) {
    const float b2v = b2[nw * 64 + ni * 16 + lr];
    float cm = 0.f;
    #pragma unroll
    for (int mi = 0; mi < 4; ++mi)
      #pragma unroll
      for (int rr = 0; rr < 4; ++rr) {
        const int k = mi * 16 + lg * 4 + rr;   // C layout: col=lane&15, row=(lane>>4)*4+reg
        const float v = fmaxf(acc[mi][ni][rr] + b2v, 0.f);
        cm = fmaxf(cm, k < Mc ? v : 0.f);
      }
    cm = fmaxf(cm, __shfl_xor(cm, 16, 64));
    cm = fmaxf(cm, __shfl_xor(cm, 32, 64));
    if (ln < 16) out[(size_t)cId * HIDD + nw * 64 + ni * 16 + lr] = cm;
  }
}

extern "C" void kernel_launch(void* const* d_in, const int* in_sizes, int n_in,
                              void* d_out, int out_size, void* d_ws, size_t ws_size,
                              hipStream_t stream) {
  const float* x   = (const float*)d_in[0];
  const float* pos = (const float*)d_in[1];
  const float* W1  = (const float*)d_in[3];
  const float* b1  = (const float*)d_in[4];
  const float* W2  = (const float*)d_in[5];
  const float* b2  = (const float*)d_in[6];

  float* out       = (float*)d_out;                   // [B*S, HID]
  float* pos_out   = out + (size_t)BB * SSS * HIDD;   // [B*S, 3]
  float* batch_out = pos_out + (size_t)BB * SSS * 3;  // [B*S]

  int* fps_idx        = (int*)d_ws;                               // 64 KB
  int* cnt            = (int*)((char*)d_ws + 65536);              // 64 KB
  unsigned short* W2t = (unsigned short*)((char*)d_ws + 131072);  // 32 KB
  int* nbr            = (int*)((char*)d_ws + 262144);             // 4 MB
  float* y1           = (float*)((char*)d_ws + 262144 + 4194304); // 32 MB

  k1_kernel<<<16 + 4096 + 1, 512, 0, stream>>>(x, pos, W1, W2, fps_idx, y1, W2t,
                                               pos_out, batch_out);
  bq_kernel<<<BB * SSS, 256, 0, stream>>>(pos, fps_idx, nbr, cnt);
  mlp_kernel<<<BB * SSS / 2, 256, 0, stream>>>(pos, y1, W1, b1, W2t, b2,
                                               fps_idx, nbr, cnt, out);
}